// Round 9
// baseline (318.811 us; speedup 1.0000x reference)
//
#include <hip/hip_runtime.h>
#include <cmath>

// ---------------------------------------------------------------------------
// Fused 3D SSIM, separable Gaussian 11-tap, VALID. fp32 (2,1,192,192,192).
// z-streaming slab, 512 threads, ONE output column per thread, channel-packed
// v_pk_fma_f32 math, TWO planes per phase (17 phases, 1 barrier each).
// Ladder: r5 205us (66 DS reads/phase, 0 conflicts) -> r8 178us (33 reads,
// but 14.8M conflict-cycles: b128 reads are INHERENTLY 4-way at this shape --
// 32 lanes x 16B/row = 4 lanes per bank-quartet, any permutation).
//
// Round-9 (pre-committed fallback from r8): H-reads back to b64 -- 8 B/lane
// = 2-way floor = free (m136; r5 measured 0). Keep everything r8 proved:
//   * static-W decode (r6: VALU win)
//   * C2 plane-fusion: twsC2[h][x][pl], read b64 both planes, one pkfma chain
//   * 16 B lane-stride stores (r5-proven zero-conflict pattern, verbatim)
// Layout: twsA/twsB split again, LSTR=34 pad (r5-proven). H = 55 b64 reads:
// more issue slots than r8's 33, but LDS-pipe TIME drops (22 b128@1.58x +
// 11 b64 ~ 80 b64-equiv -> 55).
//
// REVERT CUE: WRITE_SIZE ballooning (MBs->GBs) = spill (r6 signature).
// PIVOT CUE: conflicts ~0 but dur >= 175 -> conflict cycles were hidden;
//            stop LDS micro-opts, restructure critical path instead.
// DO NOT: b128 LDS reads at 32-lane row shape (r8: inherent 4-way);
//         32 B lane-stride b128 stores (r6: 4M conflicts);
//         register-prefetch W inputs (r1: -19%); global_load_lds slab
//         prefetch (r4: -20%); size=12 LDS-DMA (r3: corrupts).
// ---------------------------------------------------------------------------

#define WSZ 11
#define DIN 192
#define DOUTS 182
#define TH 16              // tile height (output rows, y)
#define TWD 32             // tile width  (output cols, x)
#define IHR 26             // input rows per plane tile (TH + 10)
#define ZCH 24             // output planes per chunk
#define ZIN 34             // input planes per chunk (ZCH + 10)
#define NPH (ZIN/2)        // 17 two-plane phases
#define NTX 6              // x tiles (6*32 = 192)
#define NTY 12             // y tiles (12*16 = 192)
#define ZC 8               // z-chunks (8*24 = 192)
#define NBLK (NTX*NTY*2*ZC)  // 1152
#define LSTR 34            // A/B row stride in x-entries (r5-proven pad)
#define CSTR 33            // C2 row stride in x-entries (rows +2 banks)
#define WITEMS (IHR*16)    // 416 W pair-items per plane
static constexpr double SOUT = 2.0 * 182.0 * 182.0 * 182.0;  // 12,057,136

typedef float v2f __attribute__((ext_vector_type(2)));

struct G11 { float g[WSZ]; };

__device__ __forceinline__ v2f pkfma(float g, v2f v, v2f a) {
    v2f gg = {g, g};
    return __builtin_elementwise_fma(gg, v, a);
}

__device__ __forceinline__ unsigned int enc_f(float f) {
    unsigned int u = __float_as_uint(f);
    return (u & 0x80000000u) ? ~u : (u | 0x80000000u);
}
__device__ __forceinline__ float dec_f(unsigned int u) {
    return (u & 0x80000000u) ? __uint_as_float(u & 0x7FFFFFFFu) : __uint_as_float(~u);
}

// ---------------------------------------------------------------------------
__global__ void k_init(unsigned int* mm, double* sum) {
    sum[0] = 0.0;
    mm[0] = 0u;           // encoded -inf (max accumulator)
    mm[1] = 0xFFFFFFFFu;  // encoded +inf (min accumulator)
}

// ---------------------------------------------------------------------------
__global__ __launch_bounds__(256) void k_minmax(const float4* __restrict__ img1,
                                                int n4, unsigned int* mm) {
    float mx = -1e30f, mn = 1e30f;
    for (int i = blockIdx.x * blockDim.x + threadIdx.x; i < n4;
         i += gridDim.x * blockDim.x) {
        float4 v = img1[i];
        mx = fmaxf(mx, fmaxf(fmaxf(v.x, v.y), fmaxf(v.z, v.w)));
        mn = fminf(mn, fminf(fminf(v.x, v.y), fminf(v.z, v.w)));
    }
    #pragma unroll
    for (int o = 32; o; o >>= 1) {
        mx = fmaxf(mx, __shfl_down(mx, o));
        mn = fminf(mn, __shfl_down(mn, o));
    }
    __shared__ float smx[4], smn[4];
    int lane = threadIdx.x & 63, wv = threadIdx.x >> 6;
    if (lane == 0) { smx[wv] = mx; smn[wv] = mn; }
    __syncthreads();
    if (threadIdx.x == 0) {
        #pragma unroll
        for (int i = 1; i < 4; i++) { mx = fmaxf(mx, smx[i]); mn = fminf(mn, smn[i]); }
        atomicMax(&mm[0], enc_f(mx));
        atomicMin(&mm[1], enc_f(mn));
    }
}

// ---------------------------------------------------------------------------
// 512 threads, tile 32(x) x 16(y), thread owns ONE output column.
// launch_bounds(512,4): reg cap 128 -> 4 waves/SIMD (2 blocks/CU).
__global__ __launch_bounds__(512, 4) void k_ssim(const float* __restrict__ img1,
                                                 const float* __restrict__ img2,
                                                 const unsigned int* __restrict__ mm,
                                                 double* __restrict__ sum, G11 gw) {
    // r5-proven layout: twsA[h][x]=(mu1,mu2), twsB[h][x]=(E11,E22), LSTR 34.
    // E12 plane-fused: twsC2[buf][h][x] = {E12_pl0, E12_pl1}.
    // Total 70.3 KB -> 2 blocks/CU.
    __shared__ float twsA[2][2][IHR][LSTR][2];
    __shared__ float twsB[2][2][IHR][LSTR][2];
    __shared__ float twsC2[2][IHR][CSTR][2];
    __shared__ float sred[8];

    int b   = blockIdx.x;
    int twi = b % NTX;
    int thi = (b / NTX) % NTY;
    int rest = b / (NTX * NTY);
    int tc  = rest % ZC;
    int n   = rest / ZC;                 // batch 0..1
    int ow0 = twi * TWD, oh0 = thi * TH, od0 = tc * ZCH;
    int tid = threadIdx.x;
    int y = tid >> 5, x = tid & 31;      // thread owns output (y, x)

    // SSIM constants (L from img1 min/max, computed by k_minmax)
    float maxv = dec_f(mm[0]);
    float minv = dec_f(mm[1]);
    float max_val = (maxv > 128.0f) ? 255.0f : 1.0f;
    float min_val = (minv < -0.5f) ? -1.0f : 0.0f;
    float L  = max_val - min_val;
    float C1 = 0.01f * L; C1 *= C1;
    float C2 = 0.03f * L; C2 *= C2;

    bool vout = (oh0 + y < DOUTS) && (ow0 + x < DOUTS);

    // ---- Static W-item geometry (hoisted; each thread has <=2 fixed items).
    // item0: tid<416 -> (pl=0, idx=tid); tid>=416 -> (pl=1, idx=tid-416).
    // item1: only tid<320 -> (pl=1, idx=tid+96).
    int pl0  = (tid >= WITEMS) ? 1 : 0;
    int idx0 = tid - (pl0 ? WITEMS : 0);
    int wh0  = idx0 >> 4, xo0 = 2 * (idx0 & 15);
    bool has1 = (tid < 2 * WITEMS - 512);          // 320
    int idx1 = tid + 96;
    int wh1  = idx1 >> 4, xo1 = 2 * (idx1 & 15);
    // Clamped rows/cols feed only masked outputs; loads stay in-bounds.
    unsigned rowoff0 = (unsigned)(min(oh0 + wh0, DIN - 1) * DIN
                                  + min(ow0 + xo0, DIN - 12));
    unsigned rowoff1 = (unsigned)(min(oh0 + wh1, DIN - 1) * DIN
                                  + min(ow0 + xo1, DIN - 12));
    const float* i1 = img1 + (size_t)n * DIN * DIN * DIN;   // SGPR base
    const float* i2 = img2 + (size_t)n * DIN * DIN * DIN;

// One W pair-item: x-conv of 12 input floats -> 2 outputs x 5 channels.
// Lane-pair of every v2f is (img1, img2). Stores: v2f (8 B) at 16 B
// lane-stride -- byte-identical to r5's measured-zero-conflict pattern.
#define WCONV_ITEM(PL, WH, XO, OFF)                                           \
    {                                                                         \
        const float2* p1 = (const float2*)(i1 + (OFF));                       \
        const float2* p2 = (const float2*)(i2 + (OFF));                       \
        v2f p[12];                                                            \
        _Pragma("unroll")                                                     \
        for (int q = 0; q < 6; q++) {                                         \
            float2 f1 = p1[q]; float2 f2 = p2[q];                             \
            p[2*q]   = (v2f){f1.x, f2.x};                                     \
            p[2*q+1] = (v2f){f1.y, f2.y};                                     \
        }                                                                     \
        v2f amu0 = {0.f,0.f}, amu1 = {0.f,0.f};                               \
        v2f asq0 = {0.f,0.f}, asq1 = {0.f,0.f};                               \
        float a120 = 0.f, a121 = 0.f;                                         \
        _Pragma("unroll")                                                     \
        for (int k = 0; k < WSZ; k++) {                                       \
            float g = gw.g[k];                                                \
            v2f e0 = p[k], e1 = p[k + 1];                                     \
            v2f t0 = (v2f){g, g} * e0, t1 = (v2f){g, g} * e1;                 \
            amu0 += t0; amu1 += t1;                                           \
            asq0 = __builtin_elementwise_fma(t0, e0, asq0);                   \
            asq1 = __builtin_elementwise_fma(t1, e1, asq1);                   \
            a120 = fmaf(t0.x, e0.y, a120);                                    \
            a121 = fmaf(t1.x, e1.y, a121);                                    \
        }                                                                     \
        *(v2f*)&twsA[buf][PL][WH][XO][0]     = amu0;                          \
        *(v2f*)&twsA[buf][PL][WH][XO + 1][0] = amu1;                          \
        *(v2f*)&twsB[buf][PL][WH][XO][0]     = asq0;                          \
        *(v2f*)&twsB[buf][PL][WH][XO + 1][0] = asq1;                          \
        twsC2[buf][WH][XO][PL]     = a120;                                    \
        twsC2[buf][WH][XO + 1][PL] = a121;                                    \
    }

    // D-conv packed shift pipeline: index j covers output zo = zi - j.
    v2f accMu[WSZ], accE[WSZ];
    float acc12[WSZ];
    float local = 0.f;

    for (int t = 0; t < NPH; t++) {
        int buf = t & 1;
        int zb  = od0 + 2 * t;

        // ---- W phase: 832 pair-items as 2 static items/thread ----
        {
            int d0 = min(zb + pl0, DIN - 1);     // clamped planes -> masked zo
            unsigned off0 = (unsigned)(d0 * (DIN * DIN)) + rowoff0;
            WCONV_ITEM(pl0, wh0, xo0, off0);
        }
        if (has1) {
            int d1 = min(zb + 1, DIN - 1);
            unsigned off1 = (unsigned)(d1 * (DIN * DIN)) + rowoff1;
            WCONV_ITEM(1, wh1, xo1, off1);
        }
        __syncthreads();   // only barrier per phase (2 planes)

        // ---- H phase: y-conv, 5x ds_read_b64 per tap (all free patterns) --
        v2f aMu0 = {0.f,0.f}, aE0 = {0.f,0.f};
        v2f aMu1 = {0.f,0.f}, aE1 = {0.f,0.f};
        v2f c12  = {0.f,0.f};
        #pragma unroll
        for (int k = 0; k < WSZ; k++) {
            float g = gw.g[k];
            aMu0 = pkfma(g, *(const v2f*)&twsA[buf][0][y + k][x][0], aMu0);
            aE0  = pkfma(g, *(const v2f*)&twsB[buf][0][y + k][x][0], aE0);
            aMu1 = pkfma(g, *(const v2f*)&twsA[buf][1][y + k][x][0], aMu1);
            aE1  = pkfma(g, *(const v2f*)&twsB[buf][1][y + k][x][0], aE1);
            c12  = pkfma(g, *(const v2f*)&twsC2[buf][y + k][x][0], c12);
        }
        v2f mMu[2] = {aMu0, aMu1};
        v2f mE[2]  = {aE0,  aE1};
        float m12[2] = {c12.x, c12.y};
        // No second barrier: W(t+2) reuses this dbuf half only after every
        // wave passes barrier(t+1), which follows every wave's H(t).

        // ---- D shift-FMA + SSIM, once per plane ----
        #pragma unroll
        for (int pl = 0; pl < 2; pl++) {
            #pragma unroll
            for (int j = WSZ - 1; j >= 1; j--) {
                accMu[j] = pkfma(gw.g[j], mMu[pl], accMu[j-1]);
                accE[j]  = pkfma(gw.g[j], mE[pl],  accE[j-1]);
                acc12[j] = fmaf(gw.g[j], m12[pl], acc12[j-1]);
            }
            accMu[0] = (v2f){gw.g[0], gw.g[0]} * mMu[pl];
            accE[0]  = (v2f){gw.g[0], gw.g[0]} * mE[pl];
            acc12[0] = gw.g[0] * m12[pl];

            int zi = 2 * t + pl;
            if (zi >= WSZ - 1) {
                int zo = od0 + zi - (WSZ - 1);
                if (zo < DOUTS && vout) {
                    float mu1 = accMu[10].x, mu2 = accMu[10].y;
                    float mu1s = mu1 * mu1, mu2s = mu2 * mu2, mu12 = mu1 * mu2;
                    float s1  = accE[10].x - mu1s;
                    float s2  = accE[10].y - mu2s;
                    float s12 = acc12[10] - mu12;
                    float v1  = 2.f * s12 + C2;
                    float v2  = s1 + s2 + C2;
                    float num = (2.f * mu12 + C1) * v1;
                    float den = (mu1s + mu2s + C1) * v2;
                    local += num / den;
                }
            }
        }
    }
#undef WCONV_ITEM

    // ---- block reduction (8 waves) -> one f64 atomic ----
    #pragma unroll
    for (int o = 32; o; o >>= 1) local += __shfl_down(local, o);
    if ((tid & 63) == 0) sred[tid >> 6] = local;
    __syncthreads();
    if (tid == 0) {
        float tsum = 0.f;
        #pragma unroll
        for (int i = 0; i < 8; i++) tsum += sred[i];
        atomicAdd(sum, (double)tsum);
    }
}

// ---------------------------------------------------------------------------
__global__ void k_final(const double* __restrict__ sum, float* __restrict__ out) {
    out[0] = (float)(sum[0] / SOUT);
}

// ---------------------------------------------------------------------------
extern "C" void kernel_launch(void* const* d_in, const int* in_sizes, int n_in,
                              void* d_out, int out_size, void* d_ws, size_t ws_size,
                              hipStream_t stream) {
    const float* img1 = (const float*)d_in[0];
    const float* img2 = (const float*)d_in[1];
    float* out = (float*)d_out;

    char* ws = (char*)d_ws;
    double*       sum = (double*)ws;              // 8 B
    unsigned int* mm  = (unsigned int*)(ws + 8);  // 8 B

    // Gaussian weights: f64 compute, normalize, cast to f32 (matches ref).
    G11 g;
    {
        double gd[WSZ], s = 0.0;
        for (int i = 0; i < WSZ; i++) {
            double d = (double)(i - WSZ / 2);
            gd[i] = std::exp(-(d * d) / (2.0 * 1.5 * 1.5));
            s += gd[i];
        }
        for (int i = 0; i < WSZ; i++) g.g[i] = (float)(gd[i] / s);
    }

    int n_img = 2 * DIN * DIN * DIN;  // 14,155,776

    k_init<<<1, 1, 0, stream>>>(mm, sum);
    k_minmax<<<2048, 256, 0, stream>>>((const float4*)img1, n_img / 4, mm);
    k_ssim<<<NBLK, 512, 0, stream>>>(img1, img2, mm, sum, g);
    k_final<<<1, 1, 0, stream>>>(sum, out);
}

// Round 10
// 300.860 us; speedup vs baseline: 1.0597x; 1.0597x over previous
//
#include <hip/hip_runtime.h>
#include <cmath>

// ---------------------------------------------------------------------------
// Fused 3D SSIM, separable Gaussian 11-tap, VALID. fp32 (2,1,192,192,192).
// z-streaming slab, 512 threads, ONE output column per thread, channel-packed
// v_pk_fma_f32 math, TWO planes per phase, 1 barrier/phase.
// Ladder: r5 205us -> r8 178us (staticW + AB-fused b128 reads + C2-fusion;
// 14.8M conflict-cycles but HIDDEN: r9 cut conflicts to 1M with +22 DS
// instrs and got SLOWER, 185us). LDS micro-opt space is mapped: r8 is best.
//
// Round-10 change (isolated, scheduling only): Z-CHUNKS 8 -> 7 (6x28 + 24).
//   Evidence: OccupancyPercent 37.0 vs 50 cap = 0.75 = EXACTLY the grid
//   quantization 1152 blocks / 512 resident slots (2 blk/CU x 256 CU) =
//   2.25 -> makespan 3 block-rounds for 2.25 rounds of work. With 1008
//   blocks (<2x512) and dynamic dispatch, makespan ~ total-planes/slots =
//   (864x38 + 144x34)/512 = 73.7 plane-units vs 102 (-28%), and total halo
//   work DROPS (262 vs 272 planes per xy-column). Kernel body unchanged
//   except per-block phase count nph in {19,17}.
//
// REVERT CUE: WRITE_SIZE ballooning (MBs->GBs) = spill (r6 signature).
// DO NOT: b64-only H reads (r9: fewer conflicts, MORE instrs, slower);
//         32 B lane-stride b128 stores (r6: 4M conflicts);
//         register-prefetch W inputs (r1: -19%); global_load_lds slab
//         prefetch (r4: -20%); size=12 LDS-DMA (r3: corrupts).
// ---------------------------------------------------------------------------

#define WSZ 11
#define DIN 192
#define DOUTS 182
#define TH 16              // tile height (output rows, y)
#define TWD 32             // tile width  (output cols, x)
#define IHR 26             // input rows per plane tile (TH + 10)
#define ZCHB 28            // base output planes per chunk (last chunk: 24)
#define ZC 7               // z-chunks: 6x28 + 1x24 = 192
#define NTX 6              // x tiles (6*32 = 192)
#define NTY 12             // y tiles (12*16 = 192)
#define NBLK (NTX*NTY*2*ZC)  // 1008  (< 2 x 512 resident slots)
#define ABS 32             // AB slots per row (slot-permuted, no pad)
#define CSTR 33            // C2 row stride in x-entries (rows +2 banks)
#define WITEMS (IHR*16)    // 416 W pair-items per plane
static constexpr double SOUT = 2.0 * 182.0 * 182.0 * 182.0;  // 12,057,136

typedef float v2f __attribute__((ext_vector_type(2)));
typedef float v4f __attribute__((ext_vector_type(4)));

struct G11 { float g[WSZ]; };

__device__ __forceinline__ v2f pkfma(float g, v2f v, v2f a) {
    v2f gg = {g, g};
    return __builtin_elementwise_fma(gg, v, a);
}

__device__ __forceinline__ unsigned int enc_f(float f) {
    unsigned int u = __float_as_uint(f);
    return (u & 0x80000000u) ? ~u : (u | 0x80000000u);
}
__device__ __forceinline__ float dec_f(unsigned int u) {
    return (u & 0x80000000u) ? __uint_as_float(u & 0x7FFFFFFFu) : __uint_as_float(~u);
}

// ---------------------------------------------------------------------------
__global__ void k_init(unsigned int* mm, double* sum) {
    sum[0] = 0.0;
    mm[0] = 0u;           // encoded -inf (max accumulator)
    mm[1] = 0xFFFFFFFFu;  // encoded +inf (min accumulator)
}

// ---------------------------------------------------------------------------
__global__ __launch_bounds__(256) void k_minmax(const float4* __restrict__ img1,
                                                int n4, unsigned int* mm) {
    float mx = -1e30f, mn = 1e30f;
    for (int i = blockIdx.x * blockDim.x + threadIdx.x; i < n4;
         i += gridDim.x * blockDim.x) {
        float4 v = img1[i];
        mx = fmaxf(mx, fmaxf(fmaxf(v.x, v.y), fmaxf(v.z, v.w)));
        mn = fminf(mn, fminf(fminf(v.x, v.y), fminf(v.z, v.w)));
    }
    #pragma unroll
    for (int o = 32; o; o >>= 1) {
        mx = fmaxf(mx, __shfl_down(mx, o));
        mn = fminf(mn, __shfl_down(mn, o));
    }
    __shared__ float smx[4], smn[4];
    int lane = threadIdx.x & 63, wv = threadIdx.x >> 6;
    if (lane == 0) { smx[wv] = mx; smn[wv] = mn; }
    __syncthreads();
    if (threadIdx.x == 0) {
        #pragma unroll
        for (int i = 1; i < 4; i++) { mx = fmaxf(mx, smx[i]); mn = fminf(mn, smn[i]); }
        atomicMax(&mm[0], enc_f(mx));
        atomicMin(&mm[1], enc_f(mn));
    }
}

// ---------------------------------------------------------------------------
// 512 threads, tile 32(x) x 16(y), thread owns ONE output column.
// launch_bounds(512,4): reg cap 128 -> 4 waves/SIMD (2 blocks/CU).
__global__ __launch_bounds__(512, 4) void k_ssim(const float* __restrict__ img1,
                                                 const float* __restrict__ img2,
                                                 const unsigned int* __restrict__ mm,
                                                 double* __restrict__ sum, G11 gw) {
    // AB-fused, slot-permuted: twsAB[buf][pl][h][slot] = {mu1,mu2,E11,E22}
    //   slot = perm(x): even x -> x/2, odd x -> 16 + x/2.          (53.2 KB)
    // E12 plane-fused:  twsC2[buf][h][x] = {E12_pl0, E12_pl1}.     (13.7 KB)
    __shared__ float twsAB[2][2][IHR][ABS][4];
    __shared__ float twsC2[2][IHR][CSTR][2];
    __shared__ float sred[8];

    int b   = blockIdx.x;
    int twi = b % NTX;
    int thi = (b / NTX) % NTY;
    int rest = b / (NTX * NTY);
    int tc  = rest % ZC;
    int n   = rest / ZC;                 // batch 0..1
    int ow0 = twi * TWD, oh0 = thi * TH, od0 = tc * ZCHB;
    int nph = (tc == ZC - 1) ? 17 : 19;  // (24+10)/2 or (28+10)/2 phases
    int tid = threadIdx.x;
    int y = tid >> 5, x = tid & 31;      // thread owns output (y, x)
    int sx = (x & 1) ? (16 + (x >> 1)) : (x >> 1);   // perm(x), loop-invariant

    // SSIM constants (L from img1 min/max, computed by k_minmax)
    float maxv = dec_f(mm[0]);
    float minv = dec_f(mm[1]);
    float max_val = (maxv > 128.0f) ? 255.0f : 1.0f;
    float min_val = (minv < -0.5f) ? -1.0f : 0.0f;
    float L  = max_val - min_val;
    float C1 = 0.01f * L; C1 *= C1;
    float C2 = 0.03f * L; C2 *= C2;

    bool vout = (oh0 + y < DOUTS) && (ow0 + x < DOUTS);

    // ---- Static W-item geometry (hoisted; each thread has <=2 fixed items).
    // item0: tid<416 -> (pl=0, idx=tid); tid>=416 -> (pl=1, idx=tid-416).
    // item1: only tid<320 -> (pl=1, idx=tid+96).
    int pl0  = (tid >= WITEMS) ? 1 : 0;
    int idx0 = tid - (pl0 ? WITEMS : 0);
    int wh0  = idx0 >> 4, sl0 = idx0 & 15, xo0 = 2 * sl0;
    bool has1 = (tid < 2 * WITEMS - 512);          // 320
    int idx1 = tid + 96;
    int wh1  = idx1 >> 4, sl1 = idx1 & 15, xo1 = 2 * sl1;
    // Clamped rows/cols feed only masked outputs; loads stay in-bounds.
    unsigned rowoff0 = (unsigned)(min(oh0 + wh0, DIN - 1) * DIN
                                  + min(ow0 + xo0, DIN - 12));
    unsigned rowoff1 = (unsigned)(min(oh0 + wh1, DIN - 1) * DIN
                                  + min(ow0 + xo1, DIN - 12));
    const float* i1 = img1 + (size_t)n * DIN * DIN * DIN;   // SGPR base
    const float* i2 = img2 + (size_t)n * DIN * DIN * DIN;

// One W pair-item: x-conv of 12 input floats -> 2 outputs x 5 channels.
// Lane-pair of every v2f is (img1, img2). Stores: 2x b128 at 16 B lane-stride
// (r5-proven bank pattern) + 2x b32 at 16 B lane-stride.
#define WCONV_ITEM(PL, WH, SL, XO, OFF)                                       \
    {                                                                         \
        const float2* p1 = (const float2*)(i1 + (OFF));                       \
        const float2* p2 = (const float2*)(i2 + (OFF));                       \
        v2f p[12];                                                            \
        _Pragma("unroll")                                                     \
        for (int q = 0; q < 6; q++) {                                         \
            float2 f1 = p1[q]; float2 f2 = p2[q];                             \
            p[2*q]   = (v2f){f1.x, f2.x};                                     \
            p[2*q+1] = (v2f){f1.y, f2.y};                                     \
        }                                                                     \
        v2f amu0 = {0.f,0.f}, amu1 = {0.f,0.f};                               \
        v2f asq0 = {0.f,0.f}, asq1 = {0.f,0.f};                               \
        float a120 = 0.f, a121 = 0.f;                                         \
        _Pragma("unroll")                                                     \
        for (int k = 0; k < WSZ; k++) {                                       \
            float g = gw.g[k];                                                \
            v2f e0 = p[k], e1 = p[k + 1];                                     \
            v2f t0 = (v2f){g, g} * e0, t1 = (v2f){g, g} * e1;                 \
            amu0 += t0; amu1 += t1;                                           \
            asq0 = __builtin_elementwise_fma(t0, e0, asq0);                   \
            asq1 = __builtin_elementwise_fma(t1, e1, asq1);                   \
            a120 = fmaf(t0.x, e0.y, a120);                                    \
            a121 = fmaf(t1.x, e1.y, a121);                                    \
        }                                                                     \
        *(v4f*)&twsAB[buf][PL][WH][SL][0]      = (v4f){amu0.x, amu0.y,        \
                                                       asq0.x, asq0.y};       \
        *(v4f*)&twsAB[buf][PL][WH][SL + 16][0] = (v4f){amu1.x, amu1.y,        \
                                                       asq1.x, asq1.y};       \
        twsC2[buf][WH][XO][PL]     = a120;                                    \
        twsC2[buf][WH][XO + 1][PL] = a121;                                    \
    }

    // D-conv packed shift pipeline: index j covers output zo = zi - j.
    v2f accMu[WSZ], accE[WSZ];
    float acc12[WSZ];
    float local = 0.f;

    for (int t = 0; t < nph; t++) {
        int buf = t & 1;
        int zb  = od0 + 2 * t;

        // ---- W phase: 832 pair-items as 2 static items/thread ----
        {
            int d0 = min(zb + pl0, DIN - 1);     // clamped planes -> masked zo
            unsigned off0 = (unsigned)(d0 * (DIN * DIN)) + rowoff0;
            WCONV_ITEM(pl0, wh0, sl0, xo0, off0);
        }
        if (has1) {
            int d1 = min(zb + 1, DIN - 1);
            unsigned off1 = (unsigned)(d1 * (DIN * DIN)) + rowoff1;
            WCONV_ITEM(1, wh1, sl1, xo1, off1);
        }
        __syncthreads();   // only barrier per phase (2 planes)

        // ---- H phase: y-conv, 2 b128 + 1 b64 per tap (both planes) ----
        v2f aMu0 = {0.f,0.f}, aE0 = {0.f,0.f};
        v2f aMu1 = {0.f,0.f}, aE1 = {0.f,0.f};
        v2f c12  = {0.f,0.f};
        #pragma unroll
        for (int k = 0; k < WSZ; k++) {
            float g = gw.g[k];
            v4f va = *(const v4f*)&twsAB[buf][0][y + k][sx][0];
            v4f vb = *(const v4f*)&twsAB[buf][1][y + k][sx][0];
            v2f cc = *(const v2f*)&twsC2[buf][y + k][x][0];
            aMu0 = pkfma(g, (v2f){va.x, va.y}, aMu0);
            aE0  = pkfma(g, (v2f){va.z, va.w}, aE0);
            aMu1 = pkfma(g, (v2f){vb.x, vb.y}, aMu1);
            aE1  = pkfma(g, (v2f){vb.z, vb.w}, aE1);
            c12  = pkfma(g, cc, c12);
        }
        v2f mMu[2] = {aMu0, aMu1};
        v2f mE[2]  = {aE0,  aE1};
        float m12[2] = {c12.x, c12.y};
        // No second barrier: W(t+2) reuses this dbuf half only after every
        // wave passes barrier(t+1), which follows every wave's H(t).

        // ---- D shift-FMA + SSIM, once per plane ----
        #pragma unroll
        for (int pl = 0; pl < 2; pl++) {
            #pragma unroll
            for (int j = WSZ - 1; j >= 1; j--) {
                accMu[j] = pkfma(gw.g[j], mMu[pl], accMu[j-1]);
                accE[j]  = pkfma(gw.g[j], mE[pl],  accE[j-1]);
                acc12[j] = fmaf(gw.g[j], m12[pl], acc12[j-1]);
            }
            accMu[0] = (v2f){gw.g[0], gw.g[0]} * mMu[pl];
            accE[0]  = (v2f){gw.g[0], gw.g[0]} * mE[pl];
            acc12[0] = gw.g[0] * m12[pl];

            int zi = 2 * t + pl;
            if (zi >= WSZ - 1) {
                int zo = od0 + zi - (WSZ - 1);
                if (zo < DOUTS && vout) {
                    float mu1 = accMu[10].x, mu2 = accMu[10].y;
                    float mu1s = mu1 * mu1, mu2s = mu2 * mu2, mu12 = mu1 * mu2;
                    float s1  = accE[10].x - mu1s;
                    float s2  = accE[10].y - mu2s;
                    float s12 = acc12[10] - mu12;
                    float v1  = 2.f * s12 + C2;
                    float v2  = s1 + s2 + C2;
                    float num = (2.f * mu12 + C1) * v1;
                    float den = (mu1s + mu2s + C1) * v2;
                    local += num / den;
                }
            }
        }
    }
#undef WCONV_ITEM

    // ---- block reduction (8 waves) -> one f64 atomic ----
    #pragma unroll
    for (int o = 32; o; o >>= 1) local += __shfl_down(local, o);
    if ((tid & 63) == 0) sred[tid >> 6] = local;
    __syncthreads();
    if (tid == 0) {
        float tsum = 0.f;
        #pragma unroll
        for (int i = 0; i < 8; i++) tsum += sred[i];
        atomicAdd(sum, (double)tsum);
    }
}

// ---------------------------------------------------------------------------
__global__ void k_final(const double* __restrict__ sum, float* __restrict__ out) {
    out[0] = (float)(sum[0] / SOUT);
}

// ---------------------------------------------------------------------------
extern "C" void kernel_launch(void* const* d_in, const int* in_sizes, int n_in,
                              void* d_out, int out_size, void* d_ws, size_t ws_size,
                              hipStream_t stream) {
    const float* img1 = (const float*)d_in[0];
    const float* img2 = (const float*)d_in[1];
    float* out = (float*)d_out;

    char* ws = (char*)d_ws;
    double*       sum = (double*)ws;              // 8 B
    unsigned int* mm  = (unsigned int*)(ws + 8);  // 8 B

    // Gaussian weights: f64 compute, normalize, cast to f32 (matches ref).
    G11 g;
    {
        double gd[WSZ], s = 0.0;
        for (int i = 0; i < WSZ; i++) {
            double d = (double)(i - WSZ / 2);
            gd[i] = std::exp(-(d * d) / (2.0 * 1.5 * 1.5));
            s += gd[i];
        }
        for (int i = 0; i < WSZ; i++) g.g[i] = (float)(gd[i] / s);
    }

    int n_img = 2 * DIN * DIN * DIN;  // 14,155,776

    k_init<<<1, 1, 0, stream>>>(mm, sum);
    k_minmax<<<2048, 256, 0, stream>>>((const float4*)img1, n_img / 4, mm);
    k_ssim<<<NBLK, 512, 0, stream>>>(img1, img2, mm, sum, g);
    k_final<<<1, 1, 0, stream>>>(sum, out);
}

// Round 13
// 287.725 us; speedup vs baseline: 1.1080x; 1.0456x over previous
//
#include <hip/hip_runtime.h>
#include <cmath>

// ---------------------------------------------------------------------------
// Fused 3D SSIM, separable Gaussian 11-tap, VALID. fp32 (2,1,192,192,192).
// z-streaming slab, 512 threads, ONE output column per thread, channel-packed
// v_pk_fma_f32 math, TWO planes per phase, 1 barrier/phase, ZC=7 (r10).
// Ladder: r5 205 -> r8 178 (staticW+AB-b128+C2) -> r10 160 (grid 1008).
// Counter-model note: SQ_LDS_BANK_CONFLICT mostly counts the INHERENT
// 8-words/bank floor cycles of wide DS ops (r8 est. 20M vs 14M measured),
// not fixable aliasing -- r9 "fixed" the counter and lost time. LDS is ~40%
// busy by bytes; VALU (59%) is the lead pipe.
//
// Round-11 change (isolated): TILE ASPECT 32x16 -> 16x32 (TWD=16, TH=32).
//   W-phase VALU (the largest VALU consumer, ~57%) scales with the y-halo
//   factor IHR/TH: 26/16=1.625 -> 42/32=1.3125 (-19% W VALU, -19% load
//   instrs). H/D/SSIM per output unchanged. FETCH predicted UNCHANGED
//   (x-halo worsens by the same ratio y improves; W compute follows y only).
//   LDS 57 KB (2 blocks/CU kept), grid 12x6x2x7=1008 (same quantization).
//   Bank patterns re-derived: AB row stride 17 slots (rows shift 4 banks ->
//   stores + b128 reads at 8-words/bank floor), C2 stride 17.
//   (Rounds 11+12 bench attempts both failed on container acquisition --
//    same broker error as round 7, which ran fine on resubmission; the
//    error precedes compile/launch. Resubmitted unchanged, third attempt.)
//
// REVERT CUE: WRITE_SIZE ballooning (MBs->GBs) = spill (r6 signature).
// DO NOT: b64-only H reads (r9: slower despite fewer counted conflicts);
//         register-prefetch W inputs (r1: -19%); global_load_lds slab
//         prefetch (r4: -20%); size=12 LDS-DMA (r3: corrupts).
// ---------------------------------------------------------------------------

#define WSZ 11
#define DIN 192
#define DOUTS 182
#define TH 32              // tile height (output rows, y)
#define TWD 16             // tile width  (output cols, x)
#define IHR 42             // input rows per plane tile (TH + 10)
#define ZCHB 28            // base output planes per chunk (last chunk: 24)
#define ZC 7               // z-chunks: 6x28 + 1x24 = 192
#define NTX 12             // x tiles (12*16 = 192)
#define NTY 6              // y tiles (6*32 = 192)
#define NBLK (NTX*NTY*2*ZC)  // 1008  (< 2 x 512 resident slots)
#define ABS 17             // AB slots per row (16 + 1 pad -> rows shift 4 banks)
#define CSTR 17            // C2 row stride in x-entries
#define WITEMS (IHR*8)     // 336 W pair-items per plane
static constexpr double SOUT = 2.0 * 182.0 * 182.0 * 182.0;  // 12,057,136

typedef float v2f __attribute__((ext_vector_type(2)));
typedef float v4f __attribute__((ext_vector_type(4)));

struct G11 { float g[WSZ]; };

__device__ __forceinline__ v2f pkfma(float g, v2f v, v2f a) {
    v2f gg = {g, g};
    return __builtin_elementwise_fma(gg, v, a);
}

__device__ __forceinline__ unsigned int enc_f(float f) {
    unsigned int u = __float_as_uint(f);
    return (u & 0x80000000u) ? ~u : (u | 0x80000000u);
}
__device__ __forceinline__ float dec_f(unsigned int u) {
    return (u & 0x80000000u) ? __uint_as_float(u & 0x7FFFFFFFu) : __uint_as_float(~u);
}

// ---------------------------------------------------------------------------
__global__ void k_init(unsigned int* mm, double* sum) {
    sum[0] = 0.0;
    mm[0] = 0u;           // encoded -inf (max accumulator)
    mm[1] = 0xFFFFFFFFu;  // encoded +inf (min accumulator)
}

// ---------------------------------------------------------------------------
__global__ __launch_bounds__(256) void k_minmax(const float4* __restrict__ img1,
                                                int n4, unsigned int* mm) {
    float mx = -1e30f, mn = 1e30f;
    for (int i = blockIdx.x * blockDim.x + threadIdx.x; i < n4;
         i += gridDim.x * blockDim.x) {
        float4 v = img1[i];
        mx = fmaxf(mx, fmaxf(fmaxf(v.x, v.y), fmaxf(v.z, v.w)));
        mn = fminf(mn, fminf(fminf(v.x, v.y), fminf(v.z, v.w)));
    }
    #pragma unroll
    for (int o = 32; o; o >>= 1) {
        mx = fmaxf(mx, __shfl_down(mx, o));
        mn = fminf(mn, __shfl_down(mn, o));
    }
    __shared__ float smx[4], smn[4];
    int lane = threadIdx.x & 63, wv = threadIdx.x >> 6;
    if (lane == 0) { smx[wv] = mx; smn[wv] = mn; }
    __syncthreads();
    if (threadIdx.x == 0) {
        #pragma unroll
        for (int i = 1; i < 4; i++) { mx = fmaxf(mx, smx[i]); mn = fminf(mn, smn[i]); }
        atomicMax(&mm[0], enc_f(mx));
        atomicMin(&mm[1], enc_f(mn));
    }
}

// ---------------------------------------------------------------------------
// 512 threads, tile 16(x) x 32(y), thread owns ONE output column.
// launch_bounds(512,4): reg cap 128 -> 4 waves/SIMD (2 blocks/CU).
__global__ __launch_bounds__(512, 4) void k_ssim(const float* __restrict__ img1,
                                                 const float* __restrict__ img2,
                                                 const unsigned int* __restrict__ mm,
                                                 double* __restrict__ sum, G11 gw) {
    // AB-fused, slot-permuted: twsAB[buf][pl][h][slot] = {mu1,mu2,E11,E22}
    //   slot = perm(x): even x -> x/2, odd x -> 8 + x/2; stride 17 (44.6 KB)
    // E12 plane-fused:  twsC2[buf][h][x] = {E12_pl0, E12_pl1}.     (11.2 KB)
    __shared__ float twsAB[2][2][IHR][ABS][4];
    __shared__ float twsC2[2][IHR][CSTR][2];
    __shared__ float sred[8];

    int b   = blockIdx.x;
    int twi = b % NTX;
    int thi = (b / NTX) % NTY;
    int rest = b / (NTX * NTY);
    int tc  = rest % ZC;
    int n   = rest / ZC;                 // batch 0..1
    int ow0 = twi * TWD, oh0 = thi * TH, od0 = tc * ZCHB;
    int nph = (tc == ZC - 1) ? 17 : 19;  // (24+10)/2 or (28+10)/2 phases
    int tid = threadIdx.x;
    int y = tid >> 4, x = tid & 15;      // thread owns output (y, x)
    int sx = (x & 1) ? (8 + (x >> 1)) : (x >> 1);   // perm(x), loop-invariant

    // SSIM constants (L from img1 min/max, computed by k_minmax)
    float maxv = dec_f(mm[0]);
    float minv = dec_f(mm[1]);
    float max_val = (maxv > 128.0f) ? 255.0f : 1.0f;
    float min_val = (minv < -0.5f) ? -1.0f : 0.0f;
    float L  = max_val - min_val;
    float C1 = 0.01f * L; C1 *= C1;
    float C2 = 0.03f * L; C2 *= C2;

    bool vout = (oh0 + y < DOUTS) && (ow0 + x < DOUTS);

    // ---- Static W-item geometry (hoisted; each thread has <=2 fixed items).
    // 672 pair-items/phase (2 planes x 336 = 42 rows x 8 x-pairs).
    // item0: tid<336 -> (pl=0, idx=tid); tid>=336 -> (pl=1, idx=tid-336).
    // item1: only tid<160 -> (pl=1, idx=tid+176).
    int pl0  = (tid >= WITEMS) ? 1 : 0;
    int idx0 = tid - (pl0 ? WITEMS : 0);
    int wh0  = idx0 >> 3, sl0 = idx0 & 7, xo0 = 2 * sl0;
    bool has1 = (tid < 2 * WITEMS - 512);          // 160
    int idx1 = tid + 176;
    int wh1  = idx1 >> 3, sl1 = idx1 & 7, xo1 = 2 * sl1;
    // Clamped rows/cols feed only masked outputs; loads stay in-bounds.
    unsigned rowoff0 = (unsigned)(min(oh0 + wh0, DIN - 1) * DIN
                                  + min(ow0 + xo0, DIN - 12));
    unsigned rowoff1 = (unsigned)(min(oh0 + wh1, DIN - 1) * DIN
                                  + min(ow0 + xo1, DIN - 12));
    const float* i1 = img1 + (size_t)n * DIN * DIN * DIN;   // SGPR base
    const float* i2 = img2 + (size_t)n * DIN * DIN * DIN;

// One W pair-item: x-conv of 12 input floats -> 2 outputs x 5 channels.
// Lane-pair of every v2f is (img1, img2). Stores: 2x b128 at 16 B lane-stride,
// rows shift 4 banks (ABS=17) -> 8-words/bank floor; 2x b32.
#define WCONV_ITEM(PL, WH, SL, XO, OFF)                                       \
    {                                                                         \
        const float2* p1 = (const float2*)(i1 + (OFF));                       \
        const float2* p2 = (const float2*)(i2 + (OFF));                       \
        v2f p[12];                                                            \
        _Pragma("unroll")                                                     \
        for (int q = 0; q < 6; q++) {                                         \
            float2 f1 = p1[q]; float2 f2 = p2[q];                             \
            p[2*q]   = (v2f){f1.x, f2.x};                                     \
            p[2*q+1] = (v2f){f1.y, f2.y};                                     \
        }                                                                     \
        v2f amu0 = {0.f,0.f}, amu1 = {0.f,0.f};                               \
        v2f asq0 = {0.f,0.f}, asq1 = {0.f,0.f};                               \
        float a120 = 0.f, a121 = 0.f;                                         \
        _Pragma("unroll")                                                     \
        for (int k = 0; k < WSZ; k++) {                                       \
            float g = gw.g[k];                                                \
            v2f e0 = p[k], e1 = p[k + 1];                                     \
            v2f t0 = (v2f){g, g} * e0, t1 = (v2f){g, g} * e1;                 \
            amu0 += t0; amu1 += t1;                                           \
            asq0 = __builtin_elementwise_fma(t0, e0, asq0);                   \
            asq1 = __builtin_elementwise_fma(t1, e1, asq1);                   \
            a120 = fmaf(t0.x, e0.y, a120);                                    \
            a121 = fmaf(t1.x, e1.y, a121);                                    \
        }                                                                     \
        *(v4f*)&twsAB[buf][PL][WH][SL][0]     = (v4f){amu0.x, amu0.y,         \
                                                      asq0.x, asq0.y};        \
        *(v4f*)&twsAB[buf][PL][WH][SL + 8][0] = (v4f){amu1.x, amu1.y,         \
                                                      asq1.x, asq1.y};        \
        twsC2[buf][WH][XO][PL]     = a120;                                    \
        twsC2[buf][WH][XO + 1][PL] = a121;                                    \
    }

    // D-conv packed shift pipeline: index j covers output zo = zi - j.
    v2f accMu[WSZ], accE[WSZ];
    float acc12[WSZ];
    float local = 0.f;

    for (int t = 0; t < nph; t++) {
        int buf = t & 1;
        int zb  = od0 + 2 * t;

        // ---- W phase: 672 pair-items as 2 static items/thread ----
        {
            int d0 = min(zb + pl0, DIN - 1);     // clamped planes -> masked zo
            unsigned off0 = (unsigned)(d0 * (DIN * DIN)) + rowoff0;
            WCONV_ITEM(pl0, wh0, sl0, xo0, off0);
        }
        if (has1) {
            int d1 = min(zb + 1, DIN - 1);
            unsigned off1 = (unsigned)(d1 * (DIN * DIN)) + rowoff1;
            WCONV_ITEM(1, wh1, sl1, xo1, off1);
        }
        __syncthreads();   // only barrier per phase (2 planes)

        // ---- H phase: y-conv, 2 b128 + 1 b64 per tap (both planes) ----
        v2f aMu0 = {0.f,0.f}, aE0 = {0.f,0.f};
        v2f aMu1 = {0.f,0.f}, aE1 = {0.f,0.f};
        v2f c12  = {0.f,0.f};
        #pragma unroll
        for (int k = 0; k < WSZ; k++) {
            float g = gw.g[k];
            v4f va = *(const v4f*)&twsAB[buf][0][y + k][sx][0];
            v4f vb = *(const v4f*)&twsAB[buf][1][y + k][sx][0];
            v2f cc = *(const v2f*)&twsC2[buf][y + k][x][0];
            aMu0 = pkfma(g, (v2f){va.x, va.y}, aMu0);
            aE0  = pkfma(g, (v2f){va.z, va.w}, aE0);
            aMu1 = pkfma(g, (v2f){vb.x, vb.y}, aMu1);
            aE1  = pkfma(g, (v2f){vb.z, vb.w}, aE1);
            c12  = pkfma(g, cc, c12);
        }
        v2f mMu[2] = {aMu0, aMu1};
        v2f mE[2]  = {aE0,  aE1};
        float m12[2] = {c12.x, c12.y};
        // No second barrier: W(t+2) reuses this dbuf half only after every
        // wave passes barrier(t+1), which follows every wave's H(t).

        // ---- D shift-FMA + SSIM, once per plane ----
        #pragma unroll
        for (int pl = 0; pl < 2; pl++) {
            #pragma unroll
            for (int j = WSZ - 1; j >= 1; j--) {
                accMu[j] = pkfma(gw.g[j], mMu[pl], accMu[j-1]);
                accE[j]  = pkfma(gw.g[j], mE[pl],  accE[j-1]);
                acc12[j] = fmaf(gw.g[j], m12[pl], acc12[j-1]);
            }
            accMu[0] = (v2f){gw.g[0], gw.g[0]} * mMu[pl];
            accE[0]  = (v2f){gw.g[0], gw.g[0]} * mE[pl];
            acc12[0] = gw.g[0] * m12[pl];

            int zi = 2 * t + pl;
            if (zi >= WSZ - 1) {
                int zo = od0 + zi - (WSZ - 1);
                if (zo < DOUTS && vout) {
                    float mu1 = accMu[10].x, mu2 = accMu[10].y;
                    float mu1s = mu1 * mu1, mu2s = mu2 * mu2, mu12 = mu1 * mu2;
                    float s1  = accE[10].x - mu1s;
                    float s2  = accE[10].y - mu2s;
                    float s12 = acc12[10] - mu12;
                    float v1  = 2.f * s12 + C2;
                    float v2  = s1 + s2 + C2;
                    float num = (2.f * mu12 + C1) * v1;
                    float den = (mu1s + mu2s + C1) * v2;
                    local += num / den;
                }
            }
        }
    }
#undef WCONV_ITEM

    // ---- block reduction (8 waves) -> one f64 atomic ----
    #pragma unroll
    for (int o = 32; o; o >>= 1) local += __shfl_down(local, o);
    if ((tid & 63) == 0) sred[tid >> 6] = local;
    __syncthreads();
    if (tid == 0) {
        float tsum = 0.f;
        #pragma unroll
        for (int i = 0; i < 8; i++) tsum += sred[i];
        atomicAdd(sum, (double)tsum);
    }
}

// ---------------------------------------------------------------------------
__global__ void k_final(const double* __restrict__ sum, float* __restrict__ out) {
    out[0] = (float)(sum[0] / SOUT);
}

// ---------------------------------------------------------------------------
extern "C" void kernel_launch(void* const* d_in, const int* in_sizes, int n_in,
                              void* d_out, int out_size, void* d_ws, size_t ws_size,
                              hipStream_t stream) {
    const float* img1 = (const float*)d_in[0];
    const float* img2 = (const float*)d_in[1];
    float* out = (float*)d_out;

    char* ws = (char*)d_ws;
    double*       sum = (double*)ws;              // 8 B
    unsigned int* mm  = (unsigned int*)(ws + 8);  // 8 B

    // Gaussian weights: f64 compute, normalize, cast to f32 (matches ref).
    G11 g;
    {
        double gd[WSZ], s = 0.0;
        for (int i = 0; i < WSZ; i++) {
            double d = (double)(i - WSZ / 2);
            gd[i] = std::exp(-(d * d) / (2.0 * 1.5 * 1.5));
            s += gd[i];
        }
        for (int i = 0; i < WSZ; i++) g.g[i] = (float)(gd[i] / s);
    }

    int n_img = 2 * DIN * DIN * DIN;  // 14,155,776

    k_init<<<1, 1, 0, stream>>>(mm, sum);
    k_minmax<<<2048, 256, 0, stream>>>((const float4*)img1, n_img / 4, mm);
    k_ssim<<<NBLK, 512, 0, stream>>>(img1, img2, mm, sum, g);
    k_final<<<1, 1, 0, stream>>>(sum, out);
}